// Round 12
// baseline (541.372 us; speedup 1.0000x reference)
//
#include <hip/hip_runtime.h>
#include <hip/hip_bf16.h>

#define BB 2
#define SS 2048
#define NH 32
#define NKV 8
#define GQ (NH / NKV)
#define DD 128
#define QBLK 256
#define KVBLK 64
#define NQT (SS / QBLK)
#define NTHREADS 1024
#define NWAVES 16

// +8 shorts (16B) padding on LDS leading dims (R10: conflicts 9.4e7 -> 1.8e7).
#define KPAD (DD + 8)
#define VPAD (KVBLK + 8)

typedef __bf16 bf16x8 __attribute__((ext_vector_type(8)));
typedef short short8 __attribute__((ext_vector_type(8)));
typedef float f32x4 __attribute__((ext_vector_type(4)));
typedef unsigned int u32x4 __attribute__((ext_vector_type(4)));

__device__ inline bf16x8 cvt_bf16x8(float4 a, float4 b) {
  bf16x8 r;
  r[0] = (__bf16)a.x; r[1] = (__bf16)a.y; r[2] = (__bf16)a.z; r[3] = (__bf16)a.w;
  r[4] = (__bf16)b.x; r[5] = (__bf16)b.y; r[6] = (__bf16)b.z; r[7] = (__bf16)b.w;
  return r;
}

// R10 structure with QBLK=256 / 16 waves: staging + barriers amortized over
// 2x q-rows, KV HBM re-fetch halved. Per-wave inner loop identical to R10.
__global__ __launch_bounds__(NTHREADS, 8)
void attn_mfma_q256(const float* __restrict__ qp, const float* __restrict__ kp,
                    const float* __restrict__ vp, float* __restrict__ op)
{
  __shared__ __align__(16) short kpl[KVBLK][KPAD];        // 17.4KB
  __shared__ __align__(16) short vtp[DD][VPAD];           // 18.4KB
  __shared__ __align__(16) short ppl[NWAVES][16][VPAD];   // 36.9KB

  const int tid  = threadIdx.x;
  const int wave = tid >> 6;
  const int lane = tid & 63;
  const int lhi  = lane >> 4;
  const int llo  = lane & 15;

  const int bid = blockIdx.x;
  const int bh  = bid % (BB * NH);
  const int qt  = NQT - 1 - bid / (BB * NH);   // heavy q-tiles first
  const int b   = bh / NH;
  const int h   = bh % NH;
  const int kh  = h / GQ;

  const int q0 = qt * QBLK;
  const int qw = q0 + wave * 16;

  const float scale = 0.08838834764831845f;    // 1/sqrt(128)

  // ---- Q fragments in registers ----
  bf16x8 qf[4];
  {
    const float* qrow = qp + (((size_t)b * SS + (qw + llo)) * NH + h) * DD;
    #pragma unroll
    for (int kc = 0; kc < 4; ++kc) {
      const int d0 = kc * 32 + lhi * 8;
      float4 a = *(const float4*)(qrow + d0);
      float4 c = *(const float4*)(qrow + d0 + 4);
      a.x *= scale; a.y *= scale; a.z *= scale; a.w *= scale;
      c.x *= scale; c.y *= scale; c.z *= scale; c.w *= scale;
      qf[kc] = cvt_bf16x8(a, c);
    }
  }

  f32x4 oacc[8];
  #pragma unroll
  for (int f = 0; f < 8; ++f) oacc[f] = (f32x4){0.f, 0.f, 0.f, 0.f};
  float m_i[4], l_i[4];
  #pragma unroll
  for (int j = 0; j < 4; ++j) { m_i[j] = -1e30f; l_i[j] = 0.f; }

  const int ntiles = q0 / KVBLK + QBLK / KVBLK;

  // staging coords (single pass: 1024 threads cover 1024 slots)
  const int krow = tid >> 4, kc16 = tid & 15;
  const int vdg  = tid >> 6, vtt  = tid & 63;

  for (int t = 0; t < ntiles; ++t) {
    const int t0 = t * KVBLK;
    __syncthreads();   // previous tile's compute done before overwriting LDS

    // ---- stage K tile (bf16): one 16B store per thread ----
    {
      const float* src = kp + (((size_t)b * SS + (t0 + krow)) * NKV + kh) * DD + kc16 * 8;
      float4 a = *(const float4*)src;
      float4 d = *(const float4*)(src + 4);
      *(u32x4*)&kpl[krow][kc16 * 8] = __builtin_bit_cast(u32x4, cvt_bf16x8(a, d));
    }
    // ---- stage V^T tile (bf16, scalar scatter) ----
    {
      const float* src = vp + (((size_t)b * SS + (t0 + vtt)) * NKV + kh) * DD + vdg * 8;
      float4 a  = *(const float4*)src;
      float4 d4 = *(const float4*)(src + 4);
      short8 es = __builtin_bit_cast(short8, cvt_bf16x8(a, d4));
      #pragma unroll
      for (int j = 0; j < 8; ++j) vtp[vdg * 8 + j][vtt] = es[j];
    }
    __syncthreads();

    if (t0 > qw + 15) continue;   // wave-uniform skip (barrier count unchanged)

    // ---- QK^T: S[16 q][64 t], 4 col-chunk MFMAs ----
    f32x4 sfrag[4];
    #pragma unroll
    for (int cc = 0; cc < 4; ++cc) {
      f32x4 acc = (f32x4){0.f, 0.f, 0.f, 0.f};
      const int r = cc * 16 + llo;             // K row for B-fragment
      #pragma unroll
      for (int kc = 0; kc < 4; ++kc) {
        u32x4 kb = *(const u32x4*)&kpl[r][(kc * 4 + lhi) * 8];
        acc = __builtin_amdgcn_mfma_f32_16x16x32_bf16(
                  qf[kc], __builtin_bit_cast(bf16x8, kb), acc, 0, 0, 0);
      }
      sfrag[cc] = acc;
    }

    // ---- causal mask ----
    if (t0 + KVBLK - 1 > qw) {
      #pragma unroll
      for (int cc = 0; cc < 4; ++cc)
        #pragma unroll
        for (int j = 0; j < 4; ++j) {
          const int tg = t0 + cc * 16 + llo;
          const int qg = qw + lhi * 4 + j;
          if (tg > qg) sfrag[cc][j] = -1e30f;
        }
    }

    // ---- online softmax (16-lane column groups) ----
    #pragma unroll
    for (int j = 0; j < 4; ++j) {
      float mx = fmaxf(fmaxf(sfrag[0][j], sfrag[1][j]), fmaxf(sfrag[2][j], sfrag[3][j]));
      #pragma unroll
      for (int off = 1; off < 16; off <<= 1)
        mx = fmaxf(mx, __shfl_xor(mx, off));
      const float mnew = fmaxf(m_i[j], mx);
      const float corr = __expf(m_i[j] - mnew);
      m_i[j] = mnew;
      float s = 0.f;
      #pragma unroll
      for (int cc = 0; cc < 4; ++cc) {
        const float p = __expf(sfrag[cc][j] - mnew);
        sfrag[cc][j] = p;
        s += p;
      }
      #pragma unroll
      for (int off = 1; off < 16; off <<= 1)
        s += __shfl_xor(s, off);
      l_i[j] = l_i[j] * corr + s;
      #pragma unroll
      for (int f = 0; f < 8; ++f) oacc[f][j] *= corr;
    }

    // ---- P -> per-wave LDS (scalar bf16 stores) ----
    #pragma unroll
    for (int cc = 0; cc < 4; ++cc)
      #pragma unroll
      for (int j = 0; j < 4; ++j)
        ppl[wave][lhi * 4 + j][cc * 16 + llo] =
            __builtin_bit_cast(short, (__bf16)sfrag[cc][j]);

    asm volatile("s_waitcnt lgkmcnt(0)" ::: "memory");
    __builtin_amdgcn_sched_barrier(0);

    // ---- PV: O[16 q][128 d] += P[16][64] * V[64][128] ----
    #pragma unroll
    for (int kc2 = 0; kc2 < 2; ++kc2) {
      u32x4 pa = *(const u32x4*)&ppl[wave][llo][(kc2 * 4 + lhi) * 8];
      #pragma unroll
      for (int f = 0; f < 8; ++f) {
        u32x4 vb = *(const u32x4*)&vtp[f * 16 + llo][(kc2 * 4 + lhi) * 8];
        oacc[f] = __builtin_amdgcn_mfma_f32_16x16x32_bf16(
                      __builtin_bit_cast(bf16x8, pa),
                      __builtin_bit_cast(bf16x8, vb), oacc[f], 0, 0, 0);
      }
    }
  }

  // ---- epilogue: O / l ----
  #pragma unroll
  for (int j = 0; j < 4; ++j) {
    const float inv = 1.f / l_i[j];
    const int qg = qw + lhi * 4 + j;
    float* orow = op + (((size_t)b * SS + qg) * NH + h) * DD;
    #pragma unroll
    for (int f = 0; f < 8; ++f)
      orow[f * 16 + llo] = oacc[f][j] * inv;
  }
}

extern "C" void kernel_launch(void* const* d_in, const int* in_sizes, int n_in,
                              void* d_out, int out_size, void* d_ws, size_t ws_size,
                              hipStream_t stream) {
  const float* q = (const float*)d_in[0];
  const float* k = (const float*)d_in[1];
  const float* v = (const float*)d_in[2];
  float* out = (float*)d_out;
  dim3 grid(BB * NH * NQT);   // 512 blocks
  dim3 block(NTHREADS);
  attn_mfma_q256<<<grid, block, 0, stream>>>(q, k, v, out);
}

// Round 13
// 206.315 us; speedup vs baseline: 2.6240x; 2.6240x over previous
//
#include <hip/hip_runtime.h>
#include <hip/hip_bf16.h>

#define BB 2
#define SS 2048
#define NH 32
#define NKV 8
#define GQ (NH / NKV)
#define DD 128
#define QBLK 256
#define KVBLK 64
#define NQT (SS / QBLK)
#define NTHREADS 1024
#define NWAVES 16

// +8 shorts (16B) padding on LDS leading dims (R10: conflicts 9.4e7 -> 1.8e7).
#define KPAD (DD + 8)
#define VPAD (KVBLK + 8)

typedef __bf16 bf16x8 __attribute__((ext_vector_type(8)));
typedef short short8 __attribute__((ext_vector_type(8)));
typedef float f32x4 __attribute__((ext_vector_type(4)));
typedef unsigned int u32x4 __attribute__((ext_vector_type(4)));

__device__ inline bf16x8 cvt_bf16x8(float4 a, float4 b) {
  bf16x8 r;
  r[0] = (__bf16)a.x; r[1] = (__bf16)a.y; r[2] = (__bf16)a.z; r[3] = (__bf16)a.w;
  r[4] = (__bf16)b.x; r[5] = (__bf16)b.y; r[6] = (__bf16)b.z; r[7] = (__bf16)b.w;
  return r;
}

// R12 with the spill fixed: __launch_bounds__(1024, 4) -> VGPR cap 128
// (kernel needs ~60-76; R12's (1024,8) capped at 64 -> scratch spill 2GB).
__global__ __launch_bounds__(NTHREADS, 4)
void attn_mfma_q256(const float* __restrict__ qp, const float* __restrict__ kp,
                    const float* __restrict__ vp, float* __restrict__ op)
{
  __shared__ __align__(16) short kpl[KVBLK][KPAD];        // 17.4KB
  __shared__ __align__(16) short vtp[DD][VPAD];           // 18.4KB
  __shared__ __align__(16) short ppl[NWAVES][16][VPAD];   // 36.9KB

  const int tid  = threadIdx.x;
  const int wave = tid >> 6;
  const int lane = tid & 63;
  const int lhi  = lane >> 4;
  const int llo  = lane & 15;

  const int bid = blockIdx.x;
  const int bh  = bid % (BB * NH);
  const int qt  = NQT - 1 - bid / (BB * NH);   // heavy q-tiles first
  const int b   = bh / NH;
  const int h   = bh % NH;
  const int kh  = h / GQ;

  const int q0 = qt * QBLK;
  const int qw = q0 + wave * 16;

  const float scale = 0.08838834764831845f;    // 1/sqrt(128)

  // ---- Q fragments in registers ----
  bf16x8 qf[4];
  {
    const float* qrow = qp + (((size_t)b * SS + (qw + llo)) * NH + h) * DD;
    #pragma unroll
    for (int kc = 0; kc < 4; ++kc) {
      const int d0 = kc * 32 + lhi * 8;
      float4 a = *(const float4*)(qrow + d0);
      float4 c = *(const float4*)(qrow + d0 + 4);
      a.x *= scale; a.y *= scale; a.z *= scale; a.w *= scale;
      c.x *= scale; c.y *= scale; c.z *= scale; c.w *= scale;
      qf[kc] = cvt_bf16x8(a, c);
    }
  }

  f32x4 oacc[8];
  #pragma unroll
  for (int f = 0; f < 8; ++f) oacc[f] = (f32x4){0.f, 0.f, 0.f, 0.f};
  float m_i[4], l_i[4];
  #pragma unroll
  for (int j = 0; j < 4; ++j) { m_i[j] = -1e30f; l_i[j] = 0.f; }

  const int ntiles = q0 / KVBLK + QBLK / KVBLK;

  // staging coords (single pass: 1024 threads cover 1024 slots)
  const int krow = tid >> 4, kc16 = tid & 15;
  const int vdg  = tid >> 6, vtt  = tid & 63;

  for (int t = 0; t < ntiles; ++t) {
    const int t0 = t * KVBLK;
    __syncthreads();   // previous tile's compute done before overwriting LDS

    // ---- stage K tile (bf16): one 16B store per thread ----
    {
      const float* src = kp + (((size_t)b * SS + (t0 + krow)) * NKV + kh) * DD + kc16 * 8;
      float4 a = *(const float4*)src;
      float4 d = *(const float4*)(src + 4);
      *(u32x4*)&kpl[krow][kc16 * 8] = __builtin_bit_cast(u32x4, cvt_bf16x8(a, d));
    }
    // ---- stage V^T tile (bf16, scalar scatter) ----
    {
      const float* src = vp + (((size_t)b * SS + (t0 + vtt)) * NKV + kh) * DD + vdg * 8;
      float4 a  = *(const float4*)src;
      float4 d4 = *(const float4*)(src + 4);
      short8 es = __builtin_bit_cast(short8, cvt_bf16x8(a, d4));
      #pragma unroll
      for (int j = 0; j < 8; ++j) vtp[vdg * 8 + j][vtt] = es[j];
    }
    __syncthreads();

    if (t0 > qw + 15) continue;   // wave-uniform skip (barrier count unchanged)

    // ---- QK^T: S[16 q][64 t], 4 col-chunk MFMAs ----
    f32x4 sfrag[4];
    #pragma unroll
    for (int cc = 0; cc < 4; ++cc) {
      f32x4 acc = (f32x4){0.f, 0.f, 0.f, 0.f};
      const int r = cc * 16 + llo;             // K row for B-fragment
      #pragma unroll
      for (int kc = 0; kc < 4; ++kc) {
        u32x4 kb = *(const u32x4*)&kpl[r][(kc * 4 + lhi) * 8];
        acc = __builtin_amdgcn_mfma_f32_16x16x32_bf16(
                  qf[kc], __builtin_bit_cast(bf16x8, kb), acc, 0, 0, 0);
      }
      sfrag[cc] = acc;
    }

    // ---- causal mask ----
    if (t0 + KVBLK - 1 > qw) {
      #pragma unroll
      for (int cc = 0; cc < 4; ++cc)
        #pragma unroll
        for (int j = 0; j < 4; ++j) {
          const int tg = t0 + cc * 16 + llo;
          const int qg = qw + lhi * 4 + j;
          if (tg > qg) sfrag[cc][j] = -1e30f;
        }
    }

    // ---- online softmax (16-lane column groups) ----
    #pragma unroll
    for (int j = 0; j < 4; ++j) {
      float mx = fmaxf(fmaxf(sfrag[0][j], sfrag[1][j]), fmaxf(sfrag[2][j], sfrag[3][j]));
      #pragma unroll
      for (int off = 1; off < 16; off <<= 1)
        mx = fmaxf(mx, __shfl_xor(mx, off));
      const float mnew = fmaxf(m_i[j], mx);
      const float corr = __expf(m_i[j] - mnew);
      m_i[j] = mnew;
      float s = 0.f;
      #pragma unroll
      for (int cc = 0; cc < 4; ++cc) {
        const float p = __expf(sfrag[cc][j] - mnew);
        sfrag[cc][j] = p;
        s += p;
      }
      #pragma unroll
      for (int off = 1; off < 16; off <<= 1)
        s += __shfl_xor(s, off);
      l_i[j] = l_i[j] * corr + s;
      #pragma unroll
      for (int f = 0; f < 8; ++f) oacc[f][j] *= corr;
    }

    // ---- P -> per-wave LDS (scalar bf16 stores) ----
    #pragma unroll
    for (int cc = 0; cc < 4; ++cc)
      #pragma unroll
      for (int j = 0; j < 4; ++j)
        ppl[wave][lhi * 4 + j][cc * 16 + llo] =
            __builtin_bit_cast(short, (__bf16)sfrag[cc][j]);

    asm volatile("s_waitcnt lgkmcnt(0)" ::: "memory");
    __builtin_amdgcn_sched_barrier(0);

    // ---- PV: O[16 q][128 d] += P[16][64] * V[64][128] ----
    #pragma unroll
    for (int kc2 = 0; kc2 < 2; ++kc2) {
      u32x4 pa = *(const u32x4*)&ppl[wave][llo][(kc2 * 4 + lhi) * 8];
      #pragma unroll
      for (int f = 0; f < 8; ++f) {
        u32x4 vb = *(const u32x4*)&vtp[f * 16 + llo][(kc2 * 4 + lhi) * 8];
        oacc[f] = __builtin_amdgcn_mfma_f32_16x16x32_bf16(
                      __builtin_bit_cast(bf16x8, pa),
                      __builtin_bit_cast(bf16x8, vb), oacc[f], 0, 0, 0);
      }
    }
  }

  // ---- epilogue: O / l ----
  #pragma unroll
  for (int j = 0; j < 4; ++j) {
    const float inv = 1.f / l_i[j];
    const int qg = qw + lhi * 4 + j;
    float* orow = op + (((size_t)b * SS + qg) * NH + h) * DD;
    #pragma unroll
    for (int f = 0; f < 8; ++f)
      orow[f * 16 + llo] = oacc[f][j] * inv;
  }
}

extern "C" void kernel_launch(void* const* d_in, const int* in_sizes, int n_in,
                              void* d_out, int out_size, void* d_ws, size_t ws_size,
                              hipStream_t stream) {
  const float* q = (const float*)d_in[0];
  const float* k = (const float*)d_in[1];
  const float* v = (const float*)d_in[2];
  float* out = (float*)d_out;
  dim3 grid(BB * NH * NQT);   // 512 blocks
  dim3 block(NTHREADS);
  attn_mfma_q256<<<grid, block, 0, stream>>>(q, k, v, out);
}

// Round 14
// 156.165 us; speedup vs baseline: 3.4667x; 1.3211x over previous
//
#include <hip/hip_runtime.h>
#include <hip/hip_bf16.h>

#define BB 2
#define SS 2048
#define NH 32
#define NKV 8
#define GQ (NH / NKV)
#define DD 128
#define QBLK 128
#define KVBLK 64
#define NQT (SS / QBLK)
#define NTHREADS 512

// +8 shorts (16B) padding on LDS leading dims (R10: conflicts 9.4e7 -> 1.8e7).
#define KPAD (DD + 8)
#define VPAD (KVBLK + 8)

typedef __bf16 bf16x8 __attribute__((ext_vector_type(8)));
typedef short short8 __attribute__((ext_vector_type(8)));
typedef float f32x4 __attribute__((ext_vector_type(4)));
typedef unsigned int u32x4 __attribute__((ext_vector_type(4)));

__device__ inline bf16x8 cvt_bf16x8(float4 a, float4 b) {
  bf16x8 r;
  r[0] = (__bf16)a.x; r[1] = (__bf16)a.y; r[2] = (__bf16)a.z; r[3] = (__bf16)a.w;
  r[4] = (__bf16)b.x; r[5] = (__bf16)b.y; r[6] = (__bf16)b.z; r[7] = (__bf16)b.w;
  return r;
}

// R10 base + swapped QK^T (mfma(K,Q) -> S^T): softmax row-reduce becomes
// 15 in-reg fmax + 2 shfl (was 32 shfl over ds_swizzle). Fragments, LDS
// layouts, PV, staging identical to R10.
__global__ __launch_bounds__(NTHREADS, 2)
void attn_mfma_swq(const float* __restrict__ qp, const float* __restrict__ kp,
                   const float* __restrict__ vp, float* __restrict__ op)
{
  __shared__ __align__(16) short kpl[KVBLK][KPAD];
  __shared__ __align__(16) short vtp[DD][VPAD];
  __shared__ __align__(16) short ppl[8][16][VPAD];

  const int tid  = threadIdx.x;
  const int wave = tid >> 6;
  const int lane = tid & 63;
  const int lhi  = lane >> 4;
  const int llo  = lane & 15;

  const int bid = blockIdx.x;
  const int bh  = bid % (BB * NH);
  const int qt  = NQT - 1 - bid / (BB * NH);   // heavy q-tiles first
  const int b   = bh / NH;
  const int h   = bh % NH;
  const int kh  = h / GQ;

  const int q0 = qt * QBLK;
  const int qw = q0 + wave * 16;

  const float scale = 0.08838834764831845f;    // 1/sqrt(128)

  // ---- Q fragments in registers (lane: q-row = qw+llo, k-chunk = lhi*8) ----
  bf16x8 qf[4];
  {
    const float* qrow = qp + (((size_t)b * SS + (qw + llo)) * NH + h) * DD;
    #pragma unroll
    for (int kc = 0; kc < 4; ++kc) {
      const int d0 = kc * 32 + lhi * 8;
      float4 a = *(const float4*)(qrow + d0);
      float4 c = *(const float4*)(qrow + d0 + 4);
      a.x *= scale; a.y *= scale; a.z *= scale; a.w *= scale;
      c.x *= scale; c.y *= scale; c.z *= scale; c.w *= scale;
      qf[kc] = cvt_bf16x8(a, c);
    }
  }

  f32x4 oacc[8];
  #pragma unroll
  for (int f = 0; f < 8; ++f) oacc[f] = (f32x4){0.f, 0.f, 0.f, 0.f};
  float m_i = -1e30f, l_i = 0.f;   // per-lane: running state for q = qw+llo

  const int ntiles = q0 / KVBLK + 2;

  for (int t = 0; t < ntiles; ++t) {
    const int t0 = t * KVBLK;
    __syncthreads();   // previous tile's compute done before overwriting LDS

    // ---- stage K tile (bf16): one 16B store per (row, c16) ----
    #pragma unroll
    for (int it = 0; it < 2; ++it) {
      const int c   = tid + it * NTHREADS;     // 0..1023
      const int row = c >> 4, c16 = c & 15;
      const float* src = kp + (((size_t)b * SS + (t0 + row)) * NKV + kh) * DD + c16 * 8;
      float4 a = *(const float4*)src;
      float4 d = *(const float4*)(src + 4);
      *(u32x4*)&kpl[row][c16 * 8] = __builtin_bit_cast(u32x4, cvt_bf16x8(a, d));
    }
    // ---- stage V^T tile (bf16, scalar scatter) ----
    #pragma unroll
    for (int it = 0; it < 2; ++it) {
      const int c  = tid + it * NTHREADS;
      const int dg = c >> 6, tt = c & 63;
      const float* src = vp + (((size_t)b * SS + (t0 + tt)) * NKV + kh) * DD + dg * 8;
      float4 a  = *(const float4*)src;
      float4 d4 = *(const float4*)(src + 4);
      short8 es = __builtin_bit_cast(short8, cvt_bf16x8(a, d4));
      #pragma unroll
      for (int j = 0; j < 8; ++j) vtp[dg * 8 + j][tt] = es[j];
    }
    __syncthreads();

    if (t0 > qw + 15) continue;   // wave-uniform skip (barrier count unchanged)

    // ---- QK^T swapped: sfrag[cc][j] = S[q=qw+llo][t = t0+cc*16+lhi*4+j] ----
    f32x4 sfrag[4];
    #pragma unroll
    for (int cc = 0; cc < 4; ++cc) {
      f32x4 acc = (f32x4){0.f, 0.f, 0.f, 0.f};
      const int r = cc * 16 + llo;             // K row for A-fragment
      #pragma unroll
      for (int kc = 0; kc < 4; ++kc) {
        u32x4 kb = *(const u32x4*)&kpl[r][(kc * 4 + lhi) * 8];
        acc = __builtin_amdgcn_mfma_f32_16x16x32_bf16(
                  __builtin_bit_cast(bf16x8, kb), qf[kc], acc, 0, 0, 0);
      }
      sfrag[cc] = acc;
    }

    // ---- causal mask (S^T layout) ----
    if (t0 + KVBLK - 1 > qw) {
      const int qg = qw + llo;
      #pragma unroll
      for (int cc = 0; cc < 4; ++cc)
        #pragma unroll
        for (int j = 0; j < 4; ++j) {
          const int tg = t0 + cc * 16 + lhi * 4 + j;
          if (tg > qg) sfrag[cc][j] = -1e30f;
        }
    }

    // ---- online softmax: row is lane-local (16 vals) + 2-lane-hop reduce ----
    float tmx = sfrag[0][0];
    #pragma unroll
    for (int cc = 0; cc < 4; ++cc)
      #pragma unroll
      for (int j = 0; j < 4; ++j)
        tmx = fmaxf(tmx, sfrag[cc][j]);
    tmx = fmaxf(tmx, __shfl_xor(tmx, 16));
    tmx = fmaxf(tmx, __shfl_xor(tmx, 32));
    const float mnew = fmaxf(m_i, tmx);
    const float corr = __expf(m_i - mnew);
    m_i = mnew;
    float s = 0.f;
    #pragma unroll
    for (int cc = 0; cc < 4; ++cc)
      #pragma unroll
      for (int j = 0; j < 4; ++j) {
        const float p = __expf(sfrag[cc][j] - mnew);
        sfrag[cc][j] = p;
        s += p;
      }
    s += __shfl_xor(s, 16);
    s += __shfl_xor(s, 32);
    l_i = l_i * corr + s;

    // ---- rescale O (O rows live at q = qw+lhi*4+j -> fetch corr via shfl) ----
    #pragma unroll
    for (int j = 0; j < 4; ++j) {
      const float cj = __shfl(corr, lhi * 4 + j);
      #pragma unroll
      for (int f = 0; f < 8; ++f) oacc[f][j] *= cj;
    }

    // ---- P -> per-wave LDS, same [q][t] layout PV reads ----
    #pragma unroll
    for (int cc = 0; cc < 4; ++cc)
      #pragma unroll
      for (int j = 0; j < 4; ++j)
        ppl[wave][llo][cc * 16 + lhi * 4 + j] =
            __builtin_bit_cast(short, (__bf16)sfrag[cc][j]);

    asm volatile("s_waitcnt lgkmcnt(0)" ::: "memory");
    __builtin_amdgcn_sched_barrier(0);

    // ---- PV: O[16 q][128 d] += P[16][64] * V[64][128] (unchanged) ----
    #pragma unroll
    for (int kc2 = 0; kc2 < 2; ++kc2) {
      u32x4 pa = *(const u32x4*)&ppl[wave][llo][(kc2 * 4 + lhi) * 8];
      #pragma unroll
      for (int f = 0; f < 8; ++f) {
        u32x4 vb = *(const u32x4*)&vtp[f * 16 + llo][(kc2 * 4 + lhi) * 8];
        oacc[f] = __builtin_amdgcn_mfma_f32_16x16x32_bf16(
                      __builtin_bit_cast(bf16x8, pa),
                      __builtin_bit_cast(bf16x8, vb), oacc[f], 0, 0, 0);
      }
    }
  }

  // ---- epilogue: O / l (fetch per-row l via shfl) ----
  #pragma unroll
  for (int j = 0; j < 4; ++j) {
    const float lj = __shfl(l_i, lhi * 4 + j);
    const float inv = 1.f / lj;
    const int qg = qw + lhi * 4 + j;
    float* orow = op + (((size_t)b * SS + qg) * NH + h) * DD;
    #pragma unroll
    for (int f = 0; f < 8; ++f)
      orow[f * 16 + llo] = oacc[f][j] * inv;
  }
}

extern "C" void kernel_launch(void* const* d_in, const int* in_sizes, int n_in,
                              void* d_out, int out_size, void* d_ws, size_t ws_size,
                              hipStream_t stream) {
  const float* q = (const float*)d_in[0];
  const float* k = (const float*)d_in[1];
  const float* v = (const float*)d_in[2];
  float* out = (float*)d_out;
  dim3 grid(BB * NH * NQT);   // 1024 blocks
  dim3 block(NTHREADS);
  attn_mfma_swq<<<grid, block, 0, stream>>>(q, k, v, out);
}

// Round 15
// 146.053 us; speedup vs baseline: 3.7067x; 1.0692x over previous
//
#include <hip/hip_runtime.h>
#include <hip/hip_bf16.h>

#define BB 2
#define SS 2048
#define NH 32
#define NKV 8
#define GQ (NH / NKV)
#define DD 128
#define QBLK 128
#define KVBLK 64
#define NQT (SS / QBLK)
#define NTHREADS 512

// +8 shorts (16B) padding on LDS leading dims (R10: conflicts 9.4e7 -> 1.8e7).
#define KPAD (DD + 8)
#define VPAD (KVBLK + 8)

typedef __bf16 bf16x8 __attribute__((ext_vector_type(8)));
typedef short short8 __attribute__((ext_vector_type(8)));
typedef float f32x4 __attribute__((ext_vector_type(4)));
typedef unsigned int u32x4 __attribute__((ext_vector_type(4)));
typedef unsigned short u16x4 __attribute__((ext_vector_type(4)));

__device__ inline bf16x8 cvt_bf16x8(float4 a, float4 b) {
  bf16x8 r;
  r[0] = (__bf16)a.x; r[1] = (__bf16)a.y; r[2] = (__bf16)a.z; r[3] = (__bf16)a.w;
  r[4] = (__bf16)b.x; r[5] = (__bf16)b.y; r[6] = (__bf16)b.z; r[7] = (__bf16)b.w;
  return r;
}

// R14 + LDS-pipe cuts: (1) P-store packed 16xb16 -> 4xb64;
// (2) V^T staged via coalesced per-t dword loads + 2xb128 writes
//     (was 16xb16 transpose scatter). Layouts/values identical to R14.
__global__ __launch_bounds__(NTHREADS, 2)
void attn_mfma_v2(const float* __restrict__ qp, const float* __restrict__ kp,
                  const float* __restrict__ vp, float* __restrict__ op)
{
  __shared__ __align__(16) short kpl[KVBLK][KPAD];
  __shared__ __align__(16) short vtp[DD][VPAD];
  __shared__ __align__(16) short ppl[8][16][VPAD];

  const int tid  = threadIdx.x;
  const int wave = tid >> 6;
  const int lane = tid & 63;
  const int lhi  = lane >> 4;
  const int llo  = lane & 15;

  const int bid = blockIdx.x;
  const int bh  = bid % (BB * NH);
  const int qt  = NQT - 1 - bid / (BB * NH);   // heavy q-tiles first
  const int b   = bh / NH;
  const int h   = bh % NH;
  const int kh  = h / GQ;

  const int q0 = qt * QBLK;
  const int qw = q0 + wave * 16;

  const float scale = 0.08838834764831845f;    // 1/sqrt(128)

  // ---- Q fragments in registers (lane: q-row = qw+llo, k-chunk = lhi*8) ----
  bf16x8 qf[4];
  {
    const float* qrow = qp + (((size_t)b * SS + (qw + llo)) * NH + h) * DD;
    #pragma unroll
    for (int kc = 0; kc < 4; ++kc) {
      const int d0 = kc * 32 + lhi * 8;
      float4 a = *(const float4*)(qrow + d0);
      float4 c = *(const float4*)(qrow + d0 + 4);
      a.x *= scale; a.y *= scale; a.z *= scale; a.w *= scale;
      c.x *= scale; c.y *= scale; c.z *= scale; c.w *= scale;
      qf[kc] = cvt_bf16x8(a, c);
    }
  }

  f32x4 oacc[8];
  #pragma unroll
  for (int f = 0; f < 8; ++f) oacc[f] = (f32x4){0.f, 0.f, 0.f, 0.f};
  float m_i = -1e30f, l_i = 0.f;   // per-lane running state for q = qw+llo

  const int ntiles = q0 / KVBLK + 2;

  for (int t = 0; t < ntiles; ++t) {
    const int t0 = t * KVBLK;
    __syncthreads();   // previous tile's compute done before overwriting LDS

    // ---- stage K tile (bf16): one 16B store per (row, c16) ----
    #pragma unroll
    for (int it = 0; it < 2; ++it) {
      const int c   = tid + it * NTHREADS;     // 0..1023
      const int row = c >> 4, c16 = c & 15;
      const float* src = kp + (((size_t)b * SS + (t0 + row)) * NKV + kh) * DD + c16 * 8;
      float4 a = *(const float4*)src;
      float4 d = *(const float4*)(src + 4);
      *(u32x4*)&kpl[row][c16 * 8] = __builtin_bit_cast(u32x4, cvt_bf16x8(a, d));
    }
    // ---- stage V^T tile: 8 coalesced dword loads (fixed d, 8 consecutive t)
    //      -> one b128 write of a V^T row segment ----
    #pragma unroll
    for (int it = 0; it < 2; ++it) {
      const int c  = tid + it * NTHREADS;      // 0..1023
      const int dv = c & 127, t8 = c >> 7;     // d, t-octet
      const float* src = vp + (((size_t)b * SS + (t0 + t8 * 8)) * NKV + kh) * DD + dv;
      bf16x8 e;
      #pragma unroll
      for (int i = 0; i < 8; ++i)
        e[i] = (__bf16)src[(size_t)i * (NKV * DD)];
      *(u32x4*)&vtp[dv][t8 * 8] = __builtin_bit_cast(u32x4, e);
    }
    __syncthreads();

    if (t0 > qw + 15) continue;   // wave-uniform skip (barrier count unchanged)

    // ---- QK^T swapped: sfrag[cc][j] = S[q=qw+llo][t = t0+cc*16+lhi*4+j] ----
    f32x4 sfrag[4];
    #pragma unroll
    for (int cc = 0; cc < 4; ++cc) {
      f32x4 acc = (f32x4){0.f, 0.f, 0.f, 0.f};
      const int r = cc * 16 + llo;             // K row for A-fragment
      #pragma unroll
      for (int kc = 0; kc < 4; ++kc) {
        u32x4 kb = *(const u32x4*)&kpl[r][(kc * 4 + lhi) * 8];
        acc = __builtin_amdgcn_mfma_f32_16x16x32_bf16(
                  __builtin_bit_cast(bf16x8, kb), qf[kc], acc, 0, 0, 0);
      }
      sfrag[cc] = acc;
    }

    // ---- causal mask (S^T layout) ----
    if (t0 + KVBLK - 1 > qw) {
      const int qg = qw + llo;
      #pragma unroll
      for (int cc = 0; cc < 4; ++cc)
        #pragma unroll
        for (int j = 0; j < 4; ++j) {
          const int tg = t0 + cc * 16 + lhi * 4 + j;
          if (tg > qg) sfrag[cc][j] = -1e30f;
        }
    }

    // ---- online softmax: row lane-local + 2-hop reduce ----
    float tmx = sfrag[0][0];
    #pragma unroll
    for (int cc = 0; cc < 4; ++cc)
      #pragma unroll
      for (int j = 0; j < 4; ++j)
        tmx = fmaxf(tmx, sfrag[cc][j]);
    tmx = fmaxf(tmx, __shfl_xor(tmx, 16));
    tmx = fmaxf(tmx, __shfl_xor(tmx, 32));
    const float mnew = fmaxf(m_i, tmx);
    const float corr = __expf(m_i - mnew);
    m_i = mnew;
    float s = 0.f;
    #pragma unroll
    for (int cc = 0; cc < 4; ++cc)
      #pragma unroll
      for (int j = 0; j < 4; ++j) {
        const float p = __expf(sfrag[cc][j] - mnew);
        sfrag[cc][j] = p;
        s += p;
      }
    s += __shfl_xor(s, 16);
    s += __shfl_xor(s, 32);
    l_i = l_i * corr + s;

    // ---- rescale O (per-row corr via shfl) ----
    #pragma unroll
    for (int j = 0; j < 4; ++j) {
      const float cj = __shfl(corr, lhi * 4 + j);
      #pragma unroll
      for (int f = 0; f < 8; ++f) oacc[f][j] *= cj;
    }

    // ---- P -> per-wave LDS: 4 consecutive t per cc -> one b64 store each ----
    #pragma unroll
    for (int cc = 0; cc < 4; ++cc) {
      u16x4 pk;
      pk[0] = __builtin_bit_cast(unsigned short, (__bf16)sfrag[cc][0]);
      pk[1] = __builtin_bit_cast(unsigned short, (__bf16)sfrag[cc][1]);
      pk[2] = __builtin_bit_cast(unsigned short, (__bf16)sfrag[cc][2]);
      pk[3] = __builtin_bit_cast(unsigned short, (__bf16)sfrag[cc][3]);
      *(u16x4*)&ppl[wave][llo][cc * 16 + lhi * 4] = pk;
    }

    asm volatile("s_waitcnt lgkmcnt(0)" ::: "memory");
    __builtin_amdgcn_sched_barrier(0);

    // ---- PV: O[16 q][128 d] += P[16][64] * V[64][128] (unchanged) ----
    #pragma unroll
    for (int kc2 = 0; kc2 < 2; ++kc2) {
      u32x4 pa = *(const u32x4*)&ppl[wave][llo][(kc2 * 4 + lhi) * 8];
      #pragma unroll
      for (int f = 0; f < 8; ++f) {
        u32x4 vb = *(const u32x4*)&vtp[f * 16 + llo][(kc2 * 4 + lhi) * 8];
        oacc[f] = __builtin_amdgcn_mfma_f32_16x16x32_bf16(
                      __builtin_bit_cast(bf16x8, pa),
                      __builtin_bit_cast(bf16x8, vb), oacc[f], 0, 0, 0);
      }
    }
  }

  // ---- epilogue: O / l (fetch per-row l via shfl) ----
  #pragma unroll
  for (int j = 0; j < 4; ++j) {
    const float lj = __shfl(l_i, lhi * 4 + j);
    const float inv = 1.f / lj;
    const int qg = qw + lhi * 4 + j;
    float* orow = op + (((size_t)b * SS + qg) * NH + h) * DD;
    #pragma unroll
    for (int f = 0; f < 8; ++f)
      orow[f * 16 + llo] = oacc[f][j] * inv;
  }
}

extern "C" void kernel_launch(void* const* d_in, const int* in_sizes, int n_in,
                              void* d_out, int out_size, void* d_ws, size_t ws_size,
                              hipStream_t stream) {
  const float* q = (const float*)d_in[0];
  const float* k = (const float*)d_in[1];
  const float* v = (const float*)d_in[2];
  float* out = (float*)d_out;
  dim3 grid(BB * NH * NQT);   // 1024 blocks
  dim3 block(NTHREADS);
  attn_mfma_v2<<<grid, block, 0, stream>>>(q, k, v, out);
}